// Round 8
// baseline (297.663 us; speedup 1.0000x reference)
//
#include <hip/hip_runtime.h>
#include <math.h>

#define B_    4096
#define DIN   640
#define DD    128
#define PP    12
#define INV_T 0.25f

typedef __bf16 bft;
typedef __attribute__((ext_vector_type(8))) __bf16 bf16x8;
typedef __attribute__((ext_vector_type(4))) float fx4;

// async 16B global -> LDS (DMA, vmcnt-tracked, no VGPR round trip)
__device__ __forceinline__ void gload16(const float* gp, float* lp) {
  __builtin_amdgcn_global_load_lds(
      (const __attribute__((address_space(1))) unsigned int*)gp,
      (__attribute__((address_space(3))) unsigned int*)lp,
      16, 0, 0);
}

// ---------------------------------------------------------------------------
// prep: split W into bf16 hi/lo AND pack into MFMA-fragment order so embed's
// W loads are single fully-coalesced 16B/lane (1 KB/wave contiguous) loads.
// W1F layout: [ntile 0..7][kc 0..19][hl 0..1][lane 0..63][8 bf16]
// W2F layout: [ntile 0..7][kc2 0..3][hl][lane][8 bf16] from W2[128][128].
// (unchanged from R14 — measured good: -20us embed)
// ---------------------------------------------------------------------------
__global__ __launch_bounds__(256) void prep_kernel(
    const float* __restrict__ gw1, const float* __restrict__ pw1,
    const float* __restrict__ gw2, const float* __restrict__ pw2,
    bft* __restrict__ w1fg, bft* __restrict__ w1fp,
    bft* __restrict__ w2fg, bft* __restrict__ w2fp)
{
  int id = blockIdx.x * 256 + threadIdx.x;   // 0 .. 49151
  const float* src;
  bft* dst;
  int nt, kc, hl, lane, kstride;
  if (id < 40960) {                          // W1 g then p
    const bool isg = (id < 20480);
    int f = isg ? id : (id - 20480);
    src = isg ? gw1 : pw1;
    dst = isg ? w1fg : w1fp;
    lane = f & 63;
    int q2 = f >> 6;
    hl = q2 & 1;
    int q3 = q2 >> 1;                        // nt*20 + kc, 0..159
    kc = q3 % 20; nt = q3 / 20;
    kstride = DIN;
    dst += ((size_t)(nt * 20 + kc) * 2 + hl) * 512 + lane * 8;
  } else {                                   // W2 g then p
    const bool isg = (id < 45056);
    int f = isg ? (id - 40960) : (id - 45056);
    src = isg ? gw2 : pw2;
    dst = isg ? w2fg : w2fp;
    lane = f & 63;
    int q2 = f >> 6;
    hl = q2 & 1;
    int q3 = q2 >> 1;                        // nt*4 + kc2, 0..31
    kc = q3 & 3; nt = q3 >> 2;
    kstride = DD;
    dst += ((size_t)(nt * 4 + kc) * 2 + hl) * 512 + lane * 8;
  }
  int ln = lane & 15, quad = lane >> 4;
  const float* s = src + (size_t)(nt * 16 + ln) * kstride + kc * 32 + quad * 8;
#pragma unroll
  for (int e = 0; e < 8; e++) {
    float x = s[e];
    bft h = (bft)x;
    dst[e] = hl ? (bft)(x - (float)h) : h;
  }
}

// ---------------------------------------------------------------------------
// MFMA embed (split-bf16): Y = normalize(relu(X@W1^T+b1)@W2^T+b2).
// R15 = R14 (fragment-W, counted vmcnt, b-major p) at BM=64 for occupancy.
// Evidence: R14's pipes are all <=17% busy with Occupancy 14.5% (~1.2
// waves/SIMD) — latency exposed, nothing to issue. LDS 64KB capped us at
// 2 blocks/CU and 416 blocks left 96 CUs half-loaded. BM=64: LDS 32KB ->
// __launch_bounds__(256,4) = 4 blocks/CU, grid 832 -> ~3.25 blocks/CU
// (occupancy ~40%), imbalance 4:3 instead of 2:1. R8's BM=64 regression was
// confounded by scattered 64B W loads (R14 proved those cost ~20us; their
// relative cost doubles at BM=64); fragment-packed W removes that. W re-reads
// double but are L2-resident (+5us aggregate at 34 TB/s).
// Counted-vmcnt K loop: 4-deep X slots (4x8KB aliasing h=32KB), raw s_barrier
// + s_waitcnt vmcnt(28) steady / vmcnt(20) first (GLX=2 instr/wave now:
// after GLX(c): LOADW 8 + GLX 2 + LOADW 8 + GLX 2 + LOADW 8 = 28;
// first: GLX(1) 2 + GLX(2) 2 + LOADW(0) 8 + LOADW(1) 8 = 20).
// Tail dummy loads keep counts constant; full drain before h overwrites xbuf.
// Grid: blocks 0..63 = g-stream, 64..831 = p-stream.
// ---------------------------------------------------------------------------
__global__ __launch_bounds__(256, 4) void embed_kernel(
    const float* __restrict__ ebg, const float* __restrict__ ebp,
    const bft* __restrict__ w1fg, const float* __restrict__ b1g,
    const bft* __restrict__ w2fg, const float* __restrict__ b2g,
    const bft* __restrict__ w1fp, const float* __restrict__ b1p,
    const bft* __restrict__ w2fp, const float* __restrict__ b2p,
    float* __restrict__ outg, float* __restrict__ outp)
{
  __shared__ __align__(16) bft hsm[2 * 64 * 128];   // 32768 B
  float* xbase = (float*)hsm;                 // 4 slots x [64][32] fp32 (8 KB each)
  bft* hhi = hsm;                             // 64x128 bf16 (16 KB)
  bft* hlo = hsm + 64 * 128;                  // 64x128 bf16 (16 KB)
  float* halfsq = (float*)hsm;                // aliased after h dead

  const int t = threadIdx.x;
  const int w = t >> 6, lane = t & 63;
  const int wm = w >> 1, wn = w & 1;
  const int ln = lane & 15, quad = lane >> 4;

  const float *X, *B1, *B2;
  const bft *W1F, *W2F;
  float* Y;
  long m0;
  const bool isg = (blockIdx.x < 64);
  if (isg) {
    X = ebg; W1F = w1fg; B1 = b1g; W2F = w2fg; B2 = b2g;
    Y = outg; m0 = (long)blockIdx.x * 64;
  } else {
    X = ebp; W1F = w1fp; B1 = b1p; W2F = w2fp; B2 = b2p;
    Y = outp; m0 = (long)(blockIdx.x - 64) * 64;
  }

  // staging coords: wave w fills rows w*16..w*16+15; 2 instrs of 64 lanes.
  // lane -> row_local = j*8 + (lane>>3), slot = lane&7, global kq = slot^(row&7)
  const int srow = lane >> 3;                       // 0..7
  const int skq  = (lane & 7) ^ srow;               // swizzled k-quad
  const float* xsrc = X + (size_t)(m0 + w * 16 + srow) * DIN + skq * 4;
  // LDS dest fp32 index for (wave w, instr j): (w*16 + j*8)*32 + lane*4
  const int ldst = w * 16 * 32 + lane * 4;

#define GLX(bufp, k0)                                        \
  _Pragma("unroll")                                          \
  for (int j = 0; j < 2; j++)                                \
    gload16(xsrc + (size_t)j * 8 * DIN + (k0), (bufp) + ldst + j * 8 * 32);

  // MFMA A-fragment read coords: m = wm*32+mt*16+ln, slots s0,s0^1
  const int s0 = ((quad << 1) ^ (ln & 7));

  // fragment-packed W1 pointers: global ntile = wn*4+nt; 20480 bft per ntile
  const bft* p1f[4];
#pragma unroll
  for (int nt = 0; nt < 4; nt++)
    p1f[nt] = W1F + (size_t)(wn * 4 + nt) * 20480 + lane * 8;

  fx4 acc[2][4];
#pragma unroll
  for (int mt = 0; mt < 2; mt++)
#pragma unroll
    for (int nt = 0; nt < 4; nt++) acc[mt][nt] = (fx4){0.f, 0.f, 0.f, 0.f};

  // kcv is the K-chunk index (0..19); 1024 bft per kc = hi 512 + lo 512
#define LOADW(wh, wl, kcv)                                 \
  _Pragma("unroll")                                        \
  for (int nt = 0; nt < 4; nt++) {                         \
    wh[nt] = *(const bf16x8*)(p1f[nt] + (kcv) * 1024);     \
    wl[nt] = *(const bf16x8*)(p1f[nt] + (kcv) * 1024 + 512); \
  }

#define PH1CHUNK(bufp, wh, wl)                                                         \
  {                                                                                    \
    bf16x8 ah[2], al[2];                                                               \
    _Pragma("unroll")                                                                  \
    for (int mt = 0; mt < 2; mt++) {                                                   \
      const float* rp = (bufp) + (wm * 32 + mt * 16 + ln) * 32;                        \
      fx4 x0 = *(const fx4*)(rp + s0 * 4);                                             \
      fx4 x1 = *(const fx4*)(rp + (s0 ^ 1) * 4);                                       \
      _Pragma("unroll")                                                                \
      for (int j = 0; j < 4; j++) {                                                    \
        float xv = x0[j];                                                              \
        bft hh = (bft)xv;                                                              \
        ah[mt][j] = hh;                                                                \
        al[mt][j] = (bft)(xv - (float)hh);                                             \
        float yv = x1[j];                                                              \
        bft hh2 = (bft)yv;                                                             \
        ah[mt][4 + j] = hh2;                                                           \
        al[mt][4 + j] = (bft)(yv - (float)hh2);                                        \
      }                                                                                \
    }                                                                                  \
    _Pragma("unroll")                                                                  \
    for (int mt = 0; mt < 2; mt++)                                                     \
      _Pragma("unroll")                                                                \
      for (int nt = 0; nt < 4; nt++) {                                                 \
        acc[mt][nt] = __builtin_amdgcn_mfma_f32_16x16x32_bf16(ah[mt], wh[nt], acc[mt][nt], 0, 0, 0); \
        acc[mt][nt] = __builtin_amdgcn_mfma_f32_16x16x32_bf16(al[mt], wh[nt], acc[mt][nt], 0, 0, 0); \
        acc[mt][nt] = __builtin_amdgcn_mfma_f32_16x16x32_bf16(ah[mt], wl[nt], acc[mt][nt], 0, 0, 0); \
      }                                                                                \
  }

  // ---- phase 1: counted-vmcnt pipelined K loop (20 chunks, 4 LDS slots) ----
  // HS(c): LOADW(c+1)[8], wait vmcnt(28|20)+lgkm(0), barrier, GLX(c+3)[2]
  // into slot (c+3)&3, compute slot c&3. Slot lifecycle: GLX(c+3) issued
  // post-barrier, after every wave drained its slot-((c+3)&3) ds_reads
  // (lgkmcnt(0) before the barrier). Tail dummies (kn_/kp_ -> 0) keep the
  // vmem issue counts constant so the tokens stay exact.
  bf16x8 wha[4], wla[4], whb[4], wlb[4];
  GLX(xbase, 0)                       // chunk 0 -> slot 0
  GLX(xbase + 2048, 32)               // chunk 1 -> slot 1
  GLX(xbase + 4096, 64)               // chunk 2 -> slot 2
  LOADW(wha, wla, 0)

#define HALFSTEP(c, WCH, WCL, WNH, WNL, VMTOK)                              \
  {                                                                          \
    const int kn_ = ((c) + 1 < 20) ? ((c) + 1) : 0;                          \
    LOADW(WNH, WNL, kn_)                                                     \
    asm volatile("s_waitcnt vmcnt(" VMTOK ") lgkmcnt(0)" ::: "memory");      \
    __builtin_amdgcn_s_barrier();                                            \
    __builtin_amdgcn_sched_barrier(0);                                       \
    const int kp_ = ((c) + 3 < 20) ? ((c) + 3) * 32 : 0;                     \
    float* pslot_ = xbase + ((((c) + 3) & 3) << 11);                         \
    GLX(pslot_, kp_)                                                         \
    PH1CHUNK(xbase + ((((c) & 3)) << 11), WCH, WCL)                          \
  }

  HALFSTEP(0, wha, wla, whb, wlb, "20")
  for (int kc = 1; kc < 19; kc += 2) {
    HALFSTEP(kc,     whb, wlb, wha, wla, "28")
    HALFSTEP(kc + 1, wha, wla, whb, wlb, "28")
  }
  HALFSTEP(19, whb, wlb, wha, wla, "28")

  __syncthreads();   // full drain (incl. tail dummy DMAs) before h overwrites xbuf

  // ---- bias1 + relu, split h into LDS (XOR-swizzled 16B chunks) ----
#pragma unroll
  for (int nt = 0; nt < 4; nt++) {
    float bv = B1[wn * 64 + nt * 16 + ln];
    int c8 = wn * 8 + nt * 2 + (ln >> 3);
    int c7 = ln & 7;
#pragma unroll
    for (int mt = 0; mt < 2; mt++) {
#pragma unroll
      for (int r = 0; r < 4; r++) {
        float v = fmaxf(acc[mt][nt][r] + bv, 0.f);
        bft h = (bft)v;
        bft l = (bft)(v - (float)h);
        int m = wm * 32 + mt * 16 + quad * 4 + r;
        int addr = m * 128 + ((c8 ^ (m & 15)) << 3) + c7;
        hhi[addr] = h;
        hlo[addr] = l;
      }
    }
  }

  // ---- phase 2: acc2 = h @ W2^T + b2 (split-bf16), W2F fragment-packed ----
  const bft* p2f[4];
#pragma unroll
  for (int nt = 0; nt < 4; nt++)
    p2f[nt] = W2F + (size_t)(wn * 4 + nt) * 4096 + lane * 8;

  fx4 acc2[2][4];
#pragma unroll
  for (int nt = 0; nt < 4; nt++) {
    float bv = B2[wn * 64 + nt * 16 + ln];
#pragma unroll
    for (int mt = 0; mt < 2; mt++) acc2[mt][nt] = (fx4){bv, bv, bv, bv};
  }

#define LOADW2(wh, wl, kcv)                                \
  _Pragma("unroll")                                        \
  for (int nt = 0; nt < 4; nt++) {                         \
    wh[nt] = *(const bf16x8*)(p2f[nt] + (kcv) * 1024);     \
    wl[nt] = *(const bf16x8*)(p2f[nt] + (kcv) * 1024 + 512); \
  }

#define PH2CHUNK(kcv, wh, wl)                                                          \
  {                                                                                    \
    bf16x8 ah2[2], al2[2];                                                             \
    _Pragma("unroll")                                                                  \
    for (int mt = 0; mt < 2; mt++) {                                                   \
      int m = wm * 32 + mt * 16 + ln;                                                  \
      int c8 = ((kcv) * 4 + quad) ^ (m & 15);                                          \
      ah2[mt] = *(const bf16x8*)&hhi[m * 128 + (c8 << 3)];                             \
      al2[mt] = *(const bf16x8*)&hlo[m * 128 + (c8 << 3)];                             \
    }                                                                                  \
    _Pragma("unroll")                                                                  \
    for (int mt = 0; mt < 2; mt++)                                                     \
      _Pragma("unroll")                                                                \
      for (int nt = 0; nt < 4; nt++) {                                                 \
        acc2[mt][nt] = __builtin_amdgcn_mfma_f32_16x16x32_bf16(ah2[mt], wh[nt], acc2[mt][nt], 0, 0, 0); \
        acc2[mt][nt] = __builtin_amdgcn_mfma_f32_16x16x32_bf16(al2[mt], wh[nt], acc2[mt][nt], 0, 0, 0); \
        acc2[mt][nt] = __builtin_amdgcn_mfma_f32_16x16x32_bf16(ah2[mt], wl[nt], acc2[mt][nt], 0, 0, 0); \
      }                                                                                \
  }

  bf16x8 q2ha[4], q2la[4], q2hb[4], q2lb[4];
  LOADW2(q2ha, q2la, 0)        // issued pre-barrier: barrier hides the latency
  __syncthreads();             // all h writes visible before PH2 reads
  LOADW2(q2hb, q2lb, 1)
  PH2CHUNK(0, q2ha, q2la)
  LOADW2(q2ha, q2la, 2)
  PH2CHUNK(1, q2hb, q2lb)
  LOADW2(q2hb, q2lb, 3)
  PH2CHUNK(2, q2ha, q2la)
  PH2CHUNK(3, q2hb, q2lb)
  __syncthreads();   // h reads done; halfsq may overwrite hsm

  // ---- row L2 normalize + store (g: [b][d]; p: b-major [b][l][d]) ----
#pragma unroll
  for (int mt = 0; mt < 2; mt++) {
#pragma unroll
    for (int r = 0; r < 4; r++) {
      float s = 0.f;
#pragma unroll
      for (int nt = 0; nt < 4; nt++) { float v = acc2[mt][nt][r]; s += v * v; }
      s += __shfl_xor(s, 1, 64);
      s += __shfl_xor(s, 2, 64);
      s += __shfl_xor(s, 4, 64);
      s += __shfl_xor(s, 8, 64);
      if (ln == 0) halfsq[(wm * 32 + mt * 16 + quad * 4 + r) * 2 + wn] = s;
    }
  }
  __syncthreads();
#pragma unroll
  for (int mt = 0; mt < 2; mt++) {
#pragma unroll
    for (int r = 0; r < 4; r++) {
      int row = wm * 32 + mt * 16 + quad * 4 + r;
      float rinv = 1.0f / sqrtf(halfsq[row * 2] + halfsq[row * 2 + 1]);
      long R = m0 + row;
#pragma unroll
      for (int nt = 0; nt < 4; nt++) {
        float val = acc2[mt][nt][r] * rinv;
        int col = wn * 64 + nt * 16 + ln;
        if (isg) {
          Y[R * DD + col] = val;
        } else {
          long l_ = R >> 12, b_ = R & 4095;
          Y[(b_ * PP + l_) * DD + col] = val;
        }
      }
    }
  }
}

// ---------------------------------------------------------------------------
// Symmetric KL of one D=128 row pair per 64-lane wave; inputs pre-scaled 1/T.
// sym = sum_i (pu_i - pv_i)*(au_i - av_i)  (LSE terms cancel exactly).
// No max-subtraction: args bounded (|a|<=0.25 dil, [0,1] dcl) -> exp safe.
// ---------------------------------------------------------------------------
__device__ __forceinline__ float sym_kl_row(float au0, float au1, float av0, float av1)
{
  float eu0 = __expf(au0), eu1 = __expf(au1);
  float ev0 = __expf(av0), ev1 = __expf(av1);
  float su = eu0 + eu1, sv = ev0 + ev1;
#pragma unroll
  for (int o = 32; o > 0; o >>= 1) {
    su += __shfl_xor(su, o, 64);
    sv += __shfl_xor(sv, o, 64);
  }
  float ru = 1.0f / su, rv = 1.0f / sv;
  float d0 = au0 - av0, d1 = au1 - av1;
  float part = (eu0 * ru - ev0 * rv) * d0 + (eu1 * ru - ev1 * rv) * d1;
#pragma unroll
  for (int o = 32; o > 0; o >>= 1) part += __shfl_xor(part, o, 64);
  return part;
}

// ---------------------------------------------------------------------------
// Fused loss: one wave per b. p is b-major [b][l][d] -> the 12 patch rows for
// a given b are one contiguous 6 KB span (streaming-friendly).
// ---------------------------------------------------------------------------
__global__ __launch_bounds__(256) void loss_kernel(
    const float* __restrict__ g, const float* __restrict__ p,
    float* __restrict__ pdil, float* __restrict__ pdcl)
{
  __shared__ float wd[4], wc[4];
  int w = threadIdx.x >> 6, lane = threadIdx.x & 63;
  int b = blockIdx.x * 4 + w;
  float2 pl[PP];
  float sx = 0.f, sy = 0.f;
#pragma unroll
  for (int l = 0; l < PP; l++) {
    pl[l] = *(const float2*)&p[((size_t)b * PP + l) * DD + lane * 2];
    sx += pl[l].x; sy += pl[l].y;
  }
  sx *= (1.0f / PP); sy *= (1.0f / PP);
  float2 gv = *(const float2*)&g[(size_t)b * DD + lane * 2];

  float dil = sym_kl_row(gv.x * INV_T, gv.y * INV_T, sx * INV_T, sy * INV_T) * 0.125f;

  float dcl = 0.f;
#pragma unroll
  for (int l = 0; l < PP; l++) {
    float u0 = (gv.x - pl[l].x) * (gv.x - pl[l].x) * INV_T;
    float u1 = (gv.y - pl[l].y) * (gv.y - pl[l].y) * INV_T;
    float v0 = (sx - pl[l].x) * (sx - pl[l].x) * INV_T;
    float v1 = (sy - pl[l].y) * (sy - pl[l].y) * INV_T;
    dcl += sym_kl_row(u0, u1, v0, v1);
  }
  dcl *= (1.0f / 96.0f);

  if (lane == 0) { wd[w] = dil; wc[w] = dcl; }
  __syncthreads();
  if (threadIdx.x == 0) pdil[blockIdx.x] = wd[0] + wd[1] + wd[2] + wd[3];
  if (threadIdx.x == 1) pdcl[blockIdx.x] = wc[0] + wc[1] + wc[2] + wc[3];
}

__global__ __launch_bounds__(256) void final_kernel(const float* __restrict__ pdil,
                                                    const float* __restrict__ pdcl,
                                                    float* __restrict__ out)
{
  __shared__ float red[8];
  int t = threadIdx.x;
  float s0 = 0.f, s1 = 0.f;
  for (int i = t; i < 1024; i += 256) { s0 += pdil[i]; s1 += pdcl[i]; }
#pragma unroll
  for (int o = 32; o > 0; o >>= 1) {
    s0 += __shfl_xor(s0, o, 64);
    s1 += __shfl_xor(s1, o, 64);
  }
  int wid = t >> 6, lane = t & 63;
  if (lane == 0) { red[wid] = s0; red[4 + wid] = s1; }
  __syncthreads();
  if (t == 0) out[0] = red[0] + red[1] + red[2] + red[3];
  if (t == 1) out[1] = red[4] + red[5] + red[6] + red[7];
}

extern "C" void kernel_launch(void* const* d_in, const int* in_sizes, int n_in,
                              void* d_out, int out_size, void* d_ws, size_t ws_size,
                              hipStream_t stream)
{
  const float* ebg = (const float*)d_in[0];
  const float* ebp = (const float*)d_in[1];
  const float* gw1 = (const float*)d_in[3];
  const float* gb1 = (const float*)d_in[4];
  const float* gw2 = (const float*)d_in[5];
  const float* gb2 = (const float*)d_in[6];
  const float* pw1 = (const float*)d_in[7];
  const float* pb1 = (const float*)d_in[8];
  const float* pw2 = (const float*)d_in[9];
  const float* pb2 = (const float*)d_in[10];
  float* out = (float*)d_out;

  float* ws   = (float*)d_ws;
  float* g    = ws;                           // 524288 f
  float* p    = g + (size_t)B_ * DD;          // 6291456 f  (b-major [b][l][d])
  float* pdil = p + (size_t)PP * B_ * DD;     // 1024 f
  float* pdcl = pdil + 1024;                  // 1024 f
  bft* wb   = (bft*)(pdcl + 1024);
  bft* w1fg = wb;                             // 163840 bft (8*20*2*512)
  bft* w1fp = w1fg + 163840;                  // 163840 bft
  bft* w2fg = w1fp + 163840;                  // 32768 bft (8*4*2*512)
  bft* w2fp = w2fg + 32768;                   // 32768 bft

  prep_kernel<<<192, 256, 0, stream>>>(gw1, pw1, gw2, pw2,
                                       w1fg, w1fp, w2fg, w2fp);
  embed_kernel<<<832, 256, 0, stream>>>(ebg, ebp,
                                        w1fg, gb1, w2fg, gb2,
                                        w1fp, pb1, w2fp, pb2,
                                        g, p);
  loss_kernel<<<B_ / 4, 256, 0, stream>>>(g, p, pdil, pdcl);
  final_kernel<<<1, 256, 0, stream>>>(pdil, pdcl, out);
}

// Round 9
// 252.880 us; speedup vs baseline: 1.1771x; 1.1771x over previous
//
#include <hip/hip_runtime.h>
#include <math.h>

#define B_    4096
#define DIN   640
#define DD    128
#define PP    12
#define INV_T 0.25f

typedef __bf16 bft;
typedef __attribute__((ext_vector_type(8))) __bf16 bf16x8;
typedef __attribute__((ext_vector_type(4))) float fx4;

// async 16B global -> LDS (DMA, vmcnt-tracked, no VGPR round trip)
__device__ __forceinline__ void gload16(const float* gp, float* lp) {
  __builtin_amdgcn_global_load_lds(
      (const __attribute__((address_space(1))) unsigned int*)gp,
      (__attribute__((address_space(3))) unsigned int*)lp,
      16, 0, 0);
}

// ---------------------------------------------------------------------------
// prep: split W into bf16 hi/lo AND pack into MFMA-fragment order so embed's
// W loads are single fully-coalesced 16B/lane (1 KB/wave contiguous) loads.
// W1F layout: [ntile 0..7][kc 0..19][hl 0..1][lane 0..63][8 bf16]
// W2F layout: [ntile 0..7][kc2 0..3][hl][lane][8 bf16] from W2[128][128].
// (unchanged from R14 — measured good: -20us embed)
// ---------------------------------------------------------------------------
__global__ __launch_bounds__(256) void prep_kernel(
    const float* __restrict__ gw1, const float* __restrict__ pw1,
    const float* __restrict__ gw2, const float* __restrict__ pw2,
    bft* __restrict__ w1fg, bft* __restrict__ w1fp,
    bft* __restrict__ w2fg, bft* __restrict__ w2fp)
{
  int id = blockIdx.x * 256 + threadIdx.x;   // 0 .. 49151
  const float* src;
  bft* dst;
  int nt, kc, hl, lane, kstride;
  if (id < 40960) {                          // W1 g then p
    const bool isg = (id < 20480);
    int f = isg ? id : (id - 20480);
    src = isg ? gw1 : pw1;
    dst = isg ? w1fg : w1fp;
    lane = f & 63;
    int q2 = f >> 6;
    hl = q2 & 1;
    int q3 = q2 >> 1;                        // nt*20 + kc, 0..159
    kc = q3 % 20; nt = q3 / 20;
    kstride = DIN;
    dst += ((size_t)(nt * 20 + kc) * 2 + hl) * 512 + lane * 8;
  } else {                                   // W2 g then p
    const bool isg = (id < 45056);
    int f = isg ? (id - 40960) : (id - 45056);
    src = isg ? gw2 : pw2;
    dst = isg ? w2fg : w2fp;
    lane = f & 63;
    int q2 = f >> 6;
    hl = q2 & 1;
    int q3 = q2 >> 1;                        // nt*4 + kc2, 0..31
    kc = q3 & 3; nt = q3 >> 2;
    kstride = DD;
    dst += ((size_t)(nt * 4 + kc) * 2 + hl) * 512 + lane * 8;
  }
  int ln = lane & 15, quad = lane >> 4;
  const float* s = src + (size_t)(nt * 16 + ln) * kstride + kc * 32 + quad * 8;
#pragma unroll
  for (int e = 0; e < 8; e++) {
    float x = s[e];
    bft h = (bft)x;
    dst[e] = hl ? (bft)(x - (float)h) : h;
  }
}

// ---------------------------------------------------------------------------
// MFMA embed (split-bf16): Y = normalize(relu(X@W1^T+b1)@W2^T+b2).
// R16 = R15 with the register clamp released: __launch_bounds__(256,3).
// R15's (256,4) forced VGPR_Count 120->64 -> K-loop spills to scratch
// (WRITE_SIZE 26.6->123.7 MB = the spill traffic) -> 130us despite the
// occupancy gain (30%). The allocator needs ~120 arch VGPRs (W dbuf 64 +
// staging + repack); (256,3) allows 170 so it settles ~120-128, which still
// lands on the 128-VGPR / 4-wave-per-SIMD occupancy step; LDS 32KB allows 5
// blocks/CU -> runtime occupancy still ~4 blocks/CU, now WITHOUT spills.
// Everything else identical to R15: BM=64, fragment-packed W, counted-vmcnt
// K loop (vmcnt(28) steady / 20 first; GLX=2 instr/wave), b-major p store.
// Grid: blocks 0..63 = g-stream, 64..831 = p-stream.
// ---------------------------------------------------------------------------
__global__ __launch_bounds__(256, 3) void embed_kernel(
    const float* __restrict__ ebg, const float* __restrict__ ebp,
    const bft* __restrict__ w1fg, const float* __restrict__ b1g,
    const bft* __restrict__ w2fg, const float* __restrict__ b2g,
    const bft* __restrict__ w1fp, const float* __restrict__ b1p,
    const bft* __restrict__ w2fp, const float* __restrict__ b2p,
    float* __restrict__ outg, float* __restrict__ outp)
{
  __shared__ __align__(16) bft hsm[2 * 64 * 128];   // 32768 B
  float* xbase = (float*)hsm;                 // 4 slots x [64][32] fp32 (8 KB each)
  bft* hhi = hsm;                             // 64x128 bf16 (16 KB)
  bft* hlo = hsm + 64 * 128;                  // 64x128 bf16 (16 KB)
  float* halfsq = (float*)hsm;                // aliased after h dead

  const int t = threadIdx.x;
  const int w = t >> 6, lane = t & 63;
  const int wm = w >> 1, wn = w & 1;
  const int ln = lane & 15, quad = lane >> 4;

  const float *X, *B1, *B2;
  const bft *W1F, *W2F;
  float* Y;
  long m0;
  const bool isg = (blockIdx.x < 64);
  if (isg) {
    X = ebg; W1F = w1fg; B1 = b1g; W2F = w2fg; B2 = b2g;
    Y = outg; m0 = (long)blockIdx.x * 64;
  } else {
    X = ebp; W1F = w1fp; B1 = b1p; W2F = w2fp; B2 = b2p;
    Y = outp; m0 = (long)(blockIdx.x - 64) * 64;
  }

  // staging coords: wave w fills rows w*16..w*16+15; 2 instrs of 64 lanes.
  // lane -> row_local = j*8 + (lane>>3), slot = lane&7, global kq = slot^(row&7)
  const int srow = lane >> 3;                       // 0..7
  const int skq  = (lane & 7) ^ srow;               // swizzled k-quad
  const float* xsrc = X + (size_t)(m0 + w * 16 + srow) * DIN + skq * 4;
  // LDS dest fp32 index for (wave w, instr j): (w*16 + j*8)*32 + lane*4
  const int ldst = w * 16 * 32 + lane * 4;

#define GLX(bufp, k0)                                        \
  _Pragma("unroll")                                          \
  for (int j = 0; j < 2; j++)                                \
    gload16(xsrc + (size_t)j * 8 * DIN + (k0), (bufp) + ldst + j * 8 * 32);

  // MFMA A-fragment read coords: m = wm*32+mt*16+ln, slots s0,s0^1
  const int s0 = ((quad << 1) ^ (ln & 7));

  // fragment-packed W1 pointers: global ntile = wn*4+nt; 20480 bft per ntile
  const bft* p1f[4];
#pragma unroll
  for (int nt = 0; nt < 4; nt++)
    p1f[nt] = W1F + (size_t)(wn * 4 + nt) * 20480 + lane * 8;

  fx4 acc[2][4];
#pragma unroll
  for (int mt = 0; mt < 2; mt++)
#pragma unroll
    for (int nt = 0; nt < 4; nt++) acc[mt][nt] = (fx4){0.f, 0.f, 0.f, 0.f};

  // kcv is the K-chunk index (0..19); 1024 bft per kc = hi 512 + lo 512
#define LOADW(wh, wl, kcv)                                 \
  _Pragma("unroll")                                        \
  for (int nt = 0; nt < 4; nt++) {                         \
    wh[nt] = *(const bf16x8*)(p1f[nt] + (kcv) * 1024);     \
    wl[nt] = *(const bf16x8*)(p1f[nt] + (kcv) * 1024 + 512); \
  }

#define PH1CHUNK(bufp, wh, wl)                                                         \
  {                                                                                    \
    bf16x8 ah[2], al[2];                                                               \
    _Pragma("unroll")                                                                  \
    for (int mt = 0; mt < 2; mt++) {                                                   \
      const float* rp = (bufp) + (wm * 32 + mt * 16 + ln) * 32;                        \
      fx4 x0 = *(const fx4*)(rp + s0 * 4);                                             \
      fx4 x1 = *(const fx4*)(rp + (s0 ^ 1) * 4);                                       \
      _Pragma("unroll")                                                                \
      for (int j = 0; j < 4; j++) {                                                    \
        float xv = x0[j];                                                              \
        bft hh = (bft)xv;                                                              \
        ah[mt][j] = hh;                                                                \
        al[mt][j] = (bft)(xv - (float)hh);                                             \
        float yv = x1[j];                                                              \
        bft hh2 = (bft)yv;                                                             \
        ah[mt][4 + j] = hh2;                                                           \
        al[mt][4 + j] = (bft)(yv - (float)hh2);                                        \
      }                                                                                \
    }                                                                                  \
    _Pragma("unroll")                                                                  \
    for (int mt = 0; mt < 2; mt++)                                                     \
      _Pragma("unroll")                                                                \
      for (int nt = 0; nt < 4; nt++) {                                                 \
        acc[mt][nt] = __builtin_amdgcn_mfma_f32_16x16x32_bf16(ah[mt], wh[nt], acc[mt][nt], 0, 0, 0); \
        acc[mt][nt] = __builtin_amdgcn_mfma_f32_16x16x32_bf16(al[mt], wh[nt], acc[mt][nt], 0, 0, 0); \
        acc[mt][nt] = __builtin_amdgcn_mfma_f32_16x16x32_bf16(ah[mt], wl[nt], acc[mt][nt], 0, 0, 0); \
      }                                                                                \
  }

  // ---- phase 1: counted-vmcnt pipelined K loop (20 chunks, 4 LDS slots) ----
  // HS(c): LOADW(c+1)[8], wait vmcnt(28|20)+lgkm(0), barrier, GLX(c+3)[2]
  // into slot (c+3)&3, compute slot c&3. Issued-after-GLX(c) at HS(c)'s wait:
  // steady LOADW8+GLX2+LOADW8+GLX2+LOADW8 = 28; first GLX2+GLX2+LOADW8+LOADW8
  // = 20. Slot lifecycle: GLX(c+3) issued post-barrier after every wave
  // drained its slot ds_reads (lgkmcnt(0) before barrier). Tail dummies
  // (kn_/kp_ -> 0) keep issue counts constant so tokens stay exact.
  bf16x8 wha[4], wla[4], whb[4], wlb[4];
  GLX(xbase, 0)                       // chunk 0 -> slot 0
  GLX(xbase + 2048, 32)               // chunk 1 -> slot 1
  GLX(xbase + 4096, 64)               // chunk 2 -> slot 2
  LOADW(wha, wla, 0)

#define HALFSTEP(c, WCH, WCL, WNH, WNL, VMTOK)                              \
  {                                                                          \
    const int kn_ = ((c) + 1 < 20) ? ((c) + 1) : 0;                          \
    LOADW(WNH, WNL, kn_)                                                     \
    asm volatile("s_waitcnt vmcnt(" VMTOK ") lgkmcnt(0)" ::: "memory");      \
    __builtin_amdgcn_s_barrier();                                            \
    __builtin_amdgcn_sched_barrier(0);                                       \
    const int kp_ = ((c) + 3 < 20) ? ((c) + 3) * 32 : 0;                     \
    float* pslot_ = xbase + ((((c) + 3) & 3) << 11);                         \
    GLX(pslot_, kp_)                                                         \
    PH1CHUNK(xbase + ((((c) & 3)) << 11), WCH, WCL)                          \
  }

  HALFSTEP(0, wha, wla, whb, wlb, "20")
  for (int kc = 1; kc < 19; kc += 2) {
    HALFSTEP(kc,     whb, wlb, wha, wla, "28")
    HALFSTEP(kc + 1, wha, wla, whb, wlb, "28")
  }
  HALFSTEP(19, whb, wlb, wha, wla, "28")

  __syncthreads();   // full drain (incl. tail dummy DMAs) before h overwrites xbuf

  // ---- bias1 + relu, split h into LDS (XOR-swizzled 16B chunks) ----
#pragma unroll
  for (int nt = 0; nt < 4; nt++) {
    float bv = B1[wn * 64 + nt * 16 + ln];
    int c8 = wn * 8 + nt * 2 + (ln >> 3);
    int c7 = ln & 7;
#pragma unroll
    for (int mt = 0; mt < 2; mt++) {
#pragma unroll
      for (int r = 0; r < 4; r++) {
        float v = fmaxf(acc[mt][nt][r] + bv, 0.f);
        bft h = (bft)v;
        bft l = (bft)(v - (float)h);
        int m = wm * 32 + mt * 16 + quad * 4 + r;
        int addr = m * 128 + ((c8 ^ (m & 15)) << 3) + c7;
        hhi[addr] = h;
        hlo[addr] = l;
      }
    }
  }

  // ---- phase 2: acc2 = h @ W2^T + b2 (split-bf16), W2F fragment-packed ----
  const bft* p2f[4];
#pragma unroll
  for (int nt = 0; nt < 4; nt++)
    p2f[nt] = W2F + (size_t)(wn * 4 + nt) * 4096 + lane * 8;

  fx4 acc2[2][4];
#pragma unroll
  for (int nt = 0; nt < 4; nt++) {
    float bv = B2[wn * 64 + nt * 16 + ln];
#pragma unroll
    for (int mt = 0; mt < 2; mt++) acc2[mt][nt] = (fx4){bv, bv, bv, bv};
  }

#define LOADW2(wh, wl, kcv)                                \
  _Pragma("unroll")                                        \
  for (int nt = 0; nt < 4; nt++) {                         \
    wh[nt] = *(const bf16x8*)(p2f[nt] + (kcv) * 1024);     \
    wl[nt] = *(const bf16x8*)(p2f[nt] + (kcv) * 1024 + 512); \
  }

#define PH2CHUNK(kcv, wh, wl)                                                          \
  {                                                                                    \
    bf16x8 ah2[2], al2[2];                                                             \
    _Pragma("unroll")                                                                  \
    for (int mt = 0; mt < 2; mt++) {                                                   \
      int m = wm * 32 + mt * 16 + ln;                                                  \
      int c8 = ((kcv) * 4 + quad) ^ (m & 15);                                          \
      ah2[mt] = *(const bf16x8*)&hhi[m * 128 + (c8 << 3)];                             \
      al2[mt] = *(const bf16x8*)&hlo[m * 128 + (c8 << 3)];                             \
    }                                                                                  \
    _Pragma("unroll")                                                                  \
    for (int mt = 0; mt < 2; mt++)                                                     \
      _Pragma("unroll")                                                                \
      for (int nt = 0; nt < 4; nt++) {                                                 \
        acc2[mt][nt] = __builtin_amdgcn_mfma_f32_16x16x32_bf16(ah2[mt], wh[nt], acc2[mt][nt], 0, 0, 0); \
        acc2[mt][nt] = __builtin_amdgcn_mfma_f32_16x16x32_bf16(al2[mt], wh[nt], acc2[mt][nt], 0, 0, 0); \
        acc2[mt][nt] = __builtin_amdgcn_mfma_f32_16x16x32_bf16(ah2[mt], wl[nt], acc2[mt][nt], 0, 0, 0); \
      }                                                                                \
  }

  bf16x8 q2ha[4], q2la[4], q2hb[4], q2lb[4];
  LOADW2(q2ha, q2la, 0)        // issued pre-barrier: barrier hides the latency
  __syncthreads();             // all h writes visible before PH2 reads
  LOADW2(q2hb, q2lb, 1)
  PH2CHUNK(0, q2ha, q2la)
  LOADW2(q2ha, q2la, 2)
  PH2CHUNK(1, q2hb, q2lb)
  LOADW2(q2hb, q2lb, 3)
  PH2CHUNK(2, q2ha, q2la)
  PH2CHUNK(3, q2hb, q2lb)
  __syncthreads();   // h reads done; halfsq may overwrite hsm

  // ---- row L2 normalize + store (g: [b][d]; p: b-major [b][l][d]) ----
#pragma unroll
  for (int mt = 0; mt < 2; mt++) {
#pragma unroll
    for (int r = 0; r < 4; r++) {
      float s = 0.f;
#pragma unroll
      for (int nt = 0; nt < 4; nt++) { float v = acc2[mt][nt][r]; s += v * v; }
      s += __shfl_xor(s, 1, 64);
      s += __shfl_xor(s, 2, 64);
      s += __shfl_xor(s, 4, 64);
      s += __shfl_xor(s, 8, 64);
      if (ln == 0) halfsq[(wm * 32 + mt * 16 + quad * 4 + r) * 2 + wn] = s;
    }
  }
  __syncthreads();
#pragma unroll
  for (int mt = 0; mt < 2; mt++) {
#pragma unroll
    for (int r = 0; r < 4; r++) {
      int row = wm * 32 + mt * 16 + quad * 4 + r;
      float rinv = 1.0f / sqrtf(halfsq[row * 2] + halfsq[row * 2 + 1]);
      long R = m0 + row;
#pragma unroll
      for (int nt = 0; nt < 4; nt++) {
        float val = acc2[mt][nt][r] * rinv;
        int col = wn * 64 + nt * 16 + ln;
        if (isg) {
          Y[R * DD + col] = val;
        } else {
          long l_ = R >> 12, b_ = R & 4095;
          Y[(b_ * PP + l_) * DD + col] = val;
        }
      }
    }
  }
}

// ---------------------------------------------------------------------------
// Symmetric KL of one D=128 row pair per 64-lane wave; inputs pre-scaled 1/T.
// sym = sum_i (pu_i - pv_i)*(au_i - av_i)  (LSE terms cancel exactly).
// No max-subtraction: args bounded (|a|<=0.25 dil, [0,1] dcl) -> exp safe.
// ---------------------------------------------------------------------------
__device__ __forceinline__ float sym_kl_row(float au0, float au1, float av0, float av1)
{
  float eu0 = __expf(au0), eu1 = __expf(au1);
  float ev0 = __expf(av0), ev1 = __expf(av1);
  float su = eu0 + eu1, sv = ev0 + ev1;
#pragma unroll
  for (int o = 32; o > 0; o >>= 1) {
    su += __shfl_xor(su, o, 64);
    sv += __shfl_xor(sv, o, 64);
  }
  float ru = 1.0f / su, rv = 1.0f / sv;
  float d0 = au0 - av0, d1 = au1 - av1;
  float part = (eu0 * ru - ev0 * rv) * d0 + (eu1 * ru - ev1 * rv) * d1;
#pragma unroll
  for (int o = 32; o > 0; o >>= 1) part += __shfl_xor(part, o, 64);
  return part;
}

// ---------------------------------------------------------------------------
// Fused loss: one wave per b. p is b-major [b][l][d] -> the 12 patch rows for
// a given b are one contiguous 6 KB span (streaming-friendly).
// ---------------------------------------------------------------------------
__global__ __launch_bounds__(256) void loss_kernel(
    const float* __restrict__ g, const float* __restrict__ p,
    float* __restrict__ pdil, float* __restrict__ pdcl)
{
  __shared__ float wd[4], wc[4];
  int w = threadIdx.x >> 6, lane = threadIdx.x & 63;
  int b = blockIdx.x * 4 + w;
  float2 pl[PP];
  float sx = 0.f, sy = 0.f;
#pragma unroll
  for (int l = 0; l < PP; l++) {
    pl[l] = *(const float2*)&p[((size_t)b * PP + l) * DD + lane * 2];
    sx += pl[l].x; sy += pl[l].y;
  }
  sx *= (1.0f / PP); sy *= (1.0f / PP);
  float2 gv = *(const float2*)&g[(size_t)b * DD + lane * 2];

  float dil = sym_kl_row(gv.x * INV_T, gv.y * INV_T, sx * INV_T, sy * INV_T) * 0.125f;

  float dcl = 0.f;
#pragma unroll
  for (int l = 0; l < PP; l++) {
    float u0 = (gv.x - pl[l].x) * (gv.x - pl[l].x) * INV_T;
    float u1 = (gv.y - pl[l].y) * (gv.y - pl[l].y) * INV_T;
    float v0 = (sx - pl[l].x) * (sx - pl[l].x) * INV_T;
    float v1 = (sy - pl[l].y) * (sy - pl[l].y) * INV_T;
    dcl += sym_kl_row(u0, u1, v0, v1);
  }
  dcl *= (1.0f / 96.0f);

  if (lane == 0) { wd[w] = dil; wc[w] = dcl; }
  __syncthreads();
  if (threadIdx.x == 0) pdil[blockIdx.x] = wd[0] + wd[1] + wd[2] + wd[3];
  if (threadIdx.x == 1) pdcl[blockIdx.x] = wc[0] + wc[1] + wc[2] + wc[3];
}

__global__ __launch_bounds__(256) void final_kernel(const float* __restrict__ pdil,
                                                    const float* __restrict__ pdcl,
                                                    float* __restrict__ out)
{
  __shared__ float red[8];
  int t = threadIdx.x;
  float s0 = 0.f, s1 = 0.f;
  for (int i = t; i < 1024; i += 256) { s0 += pdil[i]; s1 += pdcl[i]; }
#pragma unroll
  for (int o = 32; o > 0; o >>= 1) {
    s0 += __shfl_xor(s0, o, 64);
    s1 += __shfl_xor(s1, o, 64);
  }
  int wid = t >> 6, lane = t & 63;
  if (lane == 0) { red[wid] = s0; red[4 + wid] = s1; }
  __syncthreads();
  if (t == 0) out[0] = red[0] + red[1] + red[2] + red[3];
  if (t == 1) out[1] = red[4] + red[5] + red[6] + red[7];
}

extern "C" void kernel_launch(void* const* d_in, const int* in_sizes, int n_in,
                              void* d_out, int out_size, void* d_ws, size_t ws_size,
                              hipStream_t stream)
{
  const float* ebg = (const float*)d_in[0];
  const float* ebp = (const float*)d_in[1];
  const float* gw1 = (const float*)d_in[3];
  const float* gb1 = (const float*)d_in[4];
  const float* gw2 = (const float*)d_in[5];
  const float* gb2 = (const float*)d_in[6];
  const float* pw1 = (const float*)d_in[7];
  const float* pb1 = (const float*)d_in[8];
  const float* pw2 = (const float*)d_in[9];
  const float* pb2 = (const float*)d_in[10];
  float* out = (float*)d_out;

  float* ws   = (float*)d_ws;
  float* g    = ws;                           // 524288 f
  float* p    = g + (size_t)B_ * DD;          // 6291456 f  (b-major [b][l][d])
  float* pdil = p + (size_t)PP * B_ * DD;     // 1024 f
  float* pdcl = pdil + 1024;                  // 1024 f
  bft* wb   = (bft*)(pdcl + 1024);
  bft* w1fg = wb;                             // 163840 bft (8*20*2*512)
  bft* w1fp = w1fg + 163840;                  // 163840 bft
  bft* w2fg = w1fp + 163840;                  // 32768 bft (8*4*2*512)
  bft* w2fp = w2fg + 32768;                   // 32768 bft

  prep_kernel<<<192, 256, 0, stream>>>(gw1, pw1, gw2, pw2,
                                       w1fg, w1fp, w2fg, w2fp);
  embed_kernel<<<832, 256, 0, stream>>>(ebg, ebp,
                                        w1fg, gb1, w2fg, gb2,
                                        w1fp, pb1, w2fp, pb2,
                                        g, p);
  loss_kernel<<<B_ / 4, 256, 0, stream>>>(g, p, pdil, pdcl);
  final_kernel<<<1, 256, 0, stream>>>(pdil, pdcl, out);
}